// Round 1
// baseline (91.350 us; speedup 1.0000x reference)
//
#include <hip/hip_runtime.h>

// Cumulative max over the leading (batch) axis of a [B=64, H=56, W=56, C=256]
// fp32 tensor. y[b,h,w,c] = max_{b'<=b} x[b',h,w,c].
//
// Memory-bound: 205.5 MB read + 205.5 MB written, ideal ~65 us at 6.3 TB/s.
// One thread owns 4 consecutive channels (float4) of one (h,w) site and walks
// b serially with a running max. Lane i -> channels 4i..4i+3: coalesced 16B/lane.

#define B_DIM 64

__global__ __launch_bounds__(256) void cummax_b_kernel(
    const float4* __restrict__ in, float4* __restrict__ out, int slice4) {
    int i = blockIdx.x * blockDim.x + threadIdx.x;
    if (i >= slice4) return;

    const float4* p = in + i;
    float4* q = out + i;

    float4 m = p[0];
    q[0] = m;
#pragma unroll 8
    for (int b = 1; b < B_DIM; ++b) {
        float4 v = p[(long)b * slice4];
        m.x = fmaxf(m.x, v.x);
        m.y = fmaxf(m.y, v.y);
        m.z = fmaxf(m.z, v.z);
        m.w = fmaxf(m.w, v.w);
        q[(long)b * slice4] = m;
    }
}

extern "C" void kernel_launch(void* const* d_in, const int* in_sizes, int n_in,
                              void* d_out, int out_size, void* d_ws, size_t ws_size,
                              hipStream_t stream) {
    const float* in = (const float*)d_in[0];
    float* out = (float*)d_out;

    // out_size = B*H*W*C; per-batch slice in float4 units.
    const int slice = out_size / B_DIM;      // 802,816 floats
    const int slice4 = slice / 4;            // 200,704 float4

    const int block = 256;
    const int grid = (slice4 + block - 1) / block;   // 784 blocks

    cummax_b_kernel<<<grid, block, 0, stream>>>(
        (const float4*)in, (float4*)out, slice4);
}

// Round 3
// 77.549 us; speedup vs baseline: 1.1780x; 1.1780x over previous
//
#include <hip/hip_runtime.h>

// Cumulative max over the leading (batch) axis of a [B=64, H=56, W=56, C=256]
// fp32 tensor. y[b,h,w,c] = max_{b'<=b} x[b',h,w,c].
//
// Memory-bound: 205.5 MB read + 205.5 MB written, floor ~65 us at 6.3 TB/s.
//
// R1 was 784x256 blocks = 3.06 blocks/CU, all-resident -> 16 CUs carried 4
// blocks vs 3 (31% tail, each block ~30us of work). R2: one wave per block,
// grid = 3136 -> 12.25 blocks/CU (6% worst-case quantization; HW backfills
// if WG slots cap residency). float4 per lane keeps 16 B/lane coalescing.
// Nontemporal hints: zero reuse on either stream, don't thrash L3.
// R3 fix: __builtin_nontemporal_* needs a native clang vector type, not
// HIP's float4 class -> use ext_vector_type(4) float.

#define B_DIM 64

typedef float f32x4 __attribute__((ext_vector_type(4)));

__global__ __launch_bounds__(64) void cummax_b_kernel(
    const f32x4* __restrict__ in, f32x4* __restrict__ out, int slice4) {
    int i = blockIdx.x * 64 + threadIdx.x;
    if (i >= slice4) return;

    const f32x4* p = in + i;
    f32x4* q = out + i;

    f32x4 m;
    m.x = -INFINITY; m.y = -INFINITY; m.z = -INFINITY; m.w = -INFINITY;
#pragma unroll 16
    for (int b = 0; b < B_DIM; ++b) {
        f32x4 v = __builtin_nontemporal_load(p + (long)b * slice4);
        m.x = fmaxf(m.x, v.x);
        m.y = fmaxf(m.y, v.y);
        m.z = fmaxf(m.z, v.z);
        m.w = fmaxf(m.w, v.w);
        __builtin_nontemporal_store(m, q + (long)b * slice4);
    }
}

extern "C" void kernel_launch(void* const* d_in, const int* in_sizes, int n_in,
                              void* d_out, int out_size, void* d_ws, size_t ws_size,
                              hipStream_t stream) {
    const float* in = (const float*)d_in[0];
    float* out = (float*)d_out;

    // out_size = B*H*W*C; per-batch slice in float4 units.
    const int slice = out_size / B_DIM;      // 802,816 floats
    const int slice4 = slice / 4;            // 200,704 float4

    const int block = 64;                    // one wave per block
    const int grid = (slice4 + block - 1) / block;   // 3136 blocks

    cummax_b_kernel<<<grid, block, 0, stream>>>(
        (const f32x4*)in, (f32x4*)out, slice4);
}

// Round 4
// 64.996 us; speedup vs baseline: 1.4055x; 1.1931x over previous
//
#include <hip/hip_runtime.h>

// Cumulative max over the leading (batch) axis of a [B=64, H=56, W=56, C=256]
// fp32 tensor. y[b,h,w,c] = max_{b'<=b} x[b',h,w,c].
//
// Memory-bound: 205.5 MB read + 205.5 MB written.
//
// R1: 784x256 blocks, 91.4 us (CU quantization tail).
// R3: 3136x64 one-wave blocks + nt load/store, 77.5 us = 5.3 TB/s.
// R4 theory: input (205.5 MB) FITS in the 256 MB Infinity Cache, and the
// harness graph-replays back-to-back. Let input READS allocate in L3
// (drop the nt on loads) and keep STORES nontemporal (no-allocate) so the
// write stream doesn't evict the input. Steady-state replays then read
// from L3 and only the write stream hits HBM.

#define B_DIM 64

typedef float f32x4 __attribute__((ext_vector_type(4)));

__global__ __launch_bounds__(64) void cummax_b_kernel(
    const f32x4* __restrict__ in, f32x4* __restrict__ out, int slice4) {
    int i = blockIdx.x * 64 + threadIdx.x;
    if (i >= slice4) return;

    const f32x4* p = in + i;
    f32x4* q = out + i;

    f32x4 m;
    m.x = -INFINITY; m.y = -INFINITY; m.z = -INFINITY; m.w = -INFINITY;
#pragma unroll 16
    for (int b = 0; b < B_DIM; ++b) {
        f32x4 v = p[(long)b * slice4];                    // allocating load
        m.x = fmaxf(m.x, v.x);
        m.y = fmaxf(m.y, v.y);
        m.z = fmaxf(m.z, v.z);
        m.w = fmaxf(m.w, v.w);
        __builtin_nontemporal_store(m, q + (long)b * slice4);  // no-allocate store
    }
}

extern "C" void kernel_launch(void* const* d_in, const int* in_sizes, int n_in,
                              void* d_out, int out_size, void* d_ws, size_t ws_size,
                              hipStream_t stream) {
    const float* in = (const float*)d_in[0];
    float* out = (float*)d_out;

    // out_size = B*H*W*C; per-batch slice in float4 units.
    const int slice = out_size / B_DIM;      // 802,816 floats
    const int slice4 = slice / 4;            // 200,704 float4

    const int block = 64;                    // one wave per block
    const int grid = (slice4 + block - 1) / block;   // 3136 blocks

    cummax_b_kernel<<<grid, block, 0, stream>>>(
        (const f32x4*)in, (f32x4*)out, slice4);
}

// Round 5
// 64.773 us; speedup vs baseline: 1.4103x; 1.0034x over previous
//
#include <hip/hip_runtime.h>

// Cumulative max over the leading (batch) axis of a [B=64, H=56, W=56, C=256]
// fp32 tensor. y[b,h,w,c] = max_{b'<=b} x[b',h,w,c].
//
// R1: 784x256 blocks, 91.4 us (CU quantization tail).
// R3: 3136x64 one-wave blocks, nt load+store, 77.5 us.
// R4: allocating loads + nt stores -> half the input L3-resident across
//     graph replays (FETCH 205->100 MB), 65.0 us = ~4.7 TB/s effective.
// R5 theory: wave starvation. 12.25 waves/CU vs the ~32 the 6.3 TB/s copy
// ceiling used. Halve per-lane width to float2 -> 401,408 threads ->
// 6272 one-wave blocks = 24.5 waves/CU (2x MLP, 2% scheduling tail).
// Loads allocate (keep L3 hits), stores stay nontemporal.

#define B_DIM 64

typedef float f32x2 __attribute__((ext_vector_type(2)));

__global__ __launch_bounds__(64) void cummax_b_kernel(
    const f32x2* __restrict__ in, f32x2* __restrict__ out, int slice2) {
    int i = blockIdx.x * 64 + threadIdx.x;
    if (i >= slice2) return;

    const f32x2* p = in + i;
    f32x2* q = out + i;

    f32x2 m;
    m.x = -INFINITY; m.y = -INFINITY;
#pragma unroll 16
    for (int b = 0; b < B_DIM; ++b) {
        f32x2 v = p[(long)b * slice2];                    // allocating load
        m.x = fmaxf(m.x, v.x);
        m.y = fmaxf(m.y, v.y);
        __builtin_nontemporal_store(m, q + (long)b * slice2);  // nt store
    }
}

extern "C" void kernel_launch(void* const* d_in, const int* in_sizes, int n_in,
                              void* d_out, int out_size, void* d_ws, size_t ws_size,
                              hipStream_t stream) {
    const float* in = (const float*)d_in[0];
    float* out = (float*)d_out;

    // out_size = B*H*W*C; per-batch slice in float2 units.
    const int slice = out_size / B_DIM;      // 802,816 floats
    const int slice2 = slice / 2;            // 401,408 float2

    const int block = 64;                    // one wave per block
    const int grid = (slice2 + block - 1) / block;   // 6272 blocks

    cummax_b_kernel<<<grid, block, 0, stream>>>(
        (const f32x2*)in, (f32x2*)out, slice2);
}

// Round 6
// 63.211 us; speedup vs baseline: 1.4452x; 1.0247x over previous
//
#include <hip/hip_runtime.h>

// Cumulative max over the leading (batch) axis of a [B=64, H=56, W=56, C=256]
// fp32 tensor. y[b,h,w,c] = max_{b'<=b} x[b',h,w,c].
//
// R1: 784x256 blocks, 91.4 us.
// R3: 3136x64 one-wave blocks, nt load+store, 77.5 us.
// R4: allocating loads + builtin nt stores -> half the input stays
//     L3-resident across graph replays (FETCH 205->103 MB), 65.0 us.
// R5: 2x occupancy (float2) -> null. Not latency-bound.
// R6 experiment: total request BW is at the 6.3 TB/s copy ceiling while HBM
// is only at 4.76 TB/s. Distinguish HBM-bound vs fabric-bound: stores via
// inline asm with sc0|sc1|nt (strongest no-allocate/bypass on gfx950) so
// the 205 MB write stream stops evicting the input from the 256 MB MALL.
// If FETCH -> ~0 and dur -> ~50: HBM-bound. If FETCH -> ~0, dur ~65:
// fabric ceiling -> roofline. If FETCH ~100: no MALL lever at source level.

#define B_DIM 64

typedef float f32x2 __attribute__((ext_vector_type(2)));

__global__ __launch_bounds__(64) void cummax_b_kernel(
    const f32x2* __restrict__ in, f32x2* __restrict__ out, int slice2) {
    int i = blockIdx.x * 64 + threadIdx.x;
    if (i >= slice2) return;

    const f32x2* p = in + i;
    f32x2* q = out + i;

    f32x2 m;
    m.x = -INFINITY; m.y = -INFINITY;
#pragma unroll 16
    for (int b = 0; b < B_DIM; ++b) {
        f32x2 v = p[(long)b * slice2];                    // allocating load
        m.x = fmaxf(m.x, v.x);
        m.y = fmaxf(m.y, v.y);
        f32x2* addr = q + (long)b * slice2;
        asm volatile("global_store_dwordx2 %0, %1, off sc0 sc1 nt"
                     :: "v"(addr), "v"(m) : "memory");    // MALL-bypass store
    }
}

extern "C" void kernel_launch(void* const* d_in, const int* in_sizes, int n_in,
                              void* d_out, int out_size, void* d_ws, size_t ws_size,
                              hipStream_t stream) {
    const float* in = (const float*)d_in[0];
    float* out = (float*)d_out;

    // out_size = B*H*W*C; per-batch slice in float2 units.
    const int slice = out_size / B_DIM;      // 802,816 floats
    const int slice2 = slice / 2;            // 401,408 float2

    const int block = 64;                    // one wave per block
    const int grid = (slice2 + block - 1) / block;   // 6272 blocks

    cummax_b_kernel<<<grid, block, 0, stream>>>(
        (const f32x2*)in, (f32x2*)out, slice2);
}